// Round 1
// baseline (311.692 us; speedup 1.0000x reference)
//
#include <hip/hip_runtime.h>
#include <hip/hip_bf16.h>

// Problem constants
#define B_SZ 32
#define T_SZ 4096
#define H_SZ 256
#define BH   (B_SZ * H_SZ)   // 8192: stride (in floats) between consecutive t in enc[T,B,H]

typedef __attribute__((ext_vector_type(8))) short bf16x8;
typedef __attribute__((ext_vector_type(4))) float f32x4;

// fp32 -> bf16 bits, round-to-nearest-even (inputs are finite normals)
static __device__ __forceinline__ short f2bf(float x) {
    unsigned u = __float_as_uint(x);
    u += 0x7fffu + ((u >> 16) & 1u);
    return (short)(u >> 16);
}

static __device__ __forceinline__ bf16x8 cvt8(f32x4 a, f32x4 b) {
    bf16x8 r;
    r[0] = f2bf(a[0]); r[1] = f2bf(a[1]); r[2] = f2bf(a[2]); r[3] = f2bf(a[3]);
    r[4] = f2bf(b[0]); r[5] = f2bf(b[1]); r[6] = f2bf(b[2]); r[7] = f2bf(b[3]);
    return r;
}

// Kernel 1: hproj[b,h] = sum_k hidden[b,k]*attn_w[h, k] + attn_b[h]   (fp32, tiny)
__global__ __launch_bounds__(256) void hproj_kernel(
    const float* __restrict__ hidden, const float* __restrict__ attn_w,
    const float* __restrict__ attn_b, float* __restrict__ hp)
{
    const int b = blockIdx.x;      // 32
    const int h = threadIdx.x;     // 256
    __shared__ float hrow[H_SZ];
    hrow[h] = hidden[b * H_SZ + h];
    __syncthreads();
    const float* wrow = attn_w + (size_t)h * (2 * H_SZ);   // Wh row h (first half)
    float s = attn_b[h];
#pragma unroll 4
    for (int k = 0; k < H_SZ; k += 4) {
        f32x4 wv = *(const f32x4*)(wrow + k);
        s = fmaf(wv[0], hrow[k + 0], s);
        s = fmaf(wv[1], hrow[k + 1], s);
        s = fmaf(wv[2], hrow[k + 2], s);
        s = fmaf(wv[3], hrow[k + 3], s);
    }
    hp[b * H_SZ + h] = s;
}

// Kernel 2: fused eproj GEMM (bf16 MFMA, fp32 acc) + relu(hp + eproj) dot v -> scores[b,t]
// Grid: B * (T/64) = 2048 blocks of 256 threads (4 waves).
// Block (b, t-tile of 64). Wave w owns output tile [64 t] x [64 h], h-slice = [64w, 64w+64).
__global__ __launch_bounds__(256, 2) void attn_main(
    const float* __restrict__ enc,     // [T,B,H]
    const float* __restrict__ attn_w,  // [H, 2H]; We[h,k] = attn_w[h*512 + 256 + k]
    const float* __restrict__ hp,      // [B,H]
    const float* __restrict__ v,       // [H]
    float* __restrict__ scores)        // [B,T]
{
    const int blk  = blockIdx.x;
    const int b    = blk >> 6;            // 64 t-tiles per batch
    const int t0   = (blk & 63) << 6;
    const int tid  = threadIdx.x;
    const int w    = tid >> 6;            // wave 0..3
    const int lane = tid & 63;
    const int r    = lane & 15;           // A: m index / B: n index
    const int quad = lane >> 4;           // selects k-subchunk of 8

    f32x4 acc[4][4];
#pragma unroll
    for (int mt = 0; mt < 4; ++mt)
#pragma unroll
        for (int nt = 0; nt < 4; ++nt)
            acc[mt][nt] = (f32x4){0.f, 0.f, 0.f, 0.f};

    const float* encB  = enc + (size_t)b * H_SZ;   // E_b[t][k] = encB[t*BH + k]
    const int    hbase = w * 64;

#pragma unroll 1
    for (int kc = 0; kc < 8; ++kc) {               // K = 256 in chunks of 32
        const int k = kc * 32 + quad * 8;
        bf16x8 afrag[4], bfrag[4];
#pragma unroll
        for (int mt = 0; mt < 4; ++mt) {
            // A[m=lane&15][k=quad*8+j]: t row, 8 consecutive k
            const float* p = encB + (size_t)(t0 + mt * 16 + r) * BH + k;
            f32x4 x0 = *(const f32x4*)p;
            f32x4 x1 = *(const f32x4*)(p + 4);
            afrag[mt] = cvt8(x0, x1);
        }
#pragma unroll
        for (int nt = 0; nt < 4; ++nt) {
            // B[n=lane&15][k=quad*8+j]: We row h, 8 consecutive k (second half of attn_w row)
            const float* p = attn_w + (size_t)(hbase + nt * 16 + r) * 512 + H_SZ + k;
            f32x4 x0 = *(const f32x4*)p;
            f32x4 x1 = *(const f32x4*)(p + 4);
            bfrag[nt] = cvt8(x0, x1);
        }
#pragma unroll
        for (int mt = 0; mt < 4; ++mt)
#pragma unroll
            for (int nt = 0; nt < 4; ++nt)
                acc[mt][nt] = __builtin_amdgcn_mfma_f32_16x16x32_bf16(
                    afrag[mt], bfrag[nt], acc[mt][nt], 0, 0, 0);
    }

    // Epilogue: energy = relu(hp[b,h] + eproj), partial score = sum_h v[h]*energy
    float hpv[4], vv[4];
#pragma unroll
    for (int nt = 0; nt < 4; ++nt) {
        const int h = hbase + nt * 16 + r;         // C/D col = lane&15
        hpv[nt] = hp[b * H_SZ + h];
        vv[nt]  = v[h];
    }

    __shared__ float part[4][64];
#pragma unroll
    for (int mt = 0; mt < 4; ++mt) {
#pragma unroll
        for (int reg = 0; reg < 4; ++reg) {        // C/D row = quad*4 + reg
            float s = 0.f;
#pragma unroll
            for (int nt = 0; nt < 4; ++nt) {
                float e = hpv[nt] + acc[mt][nt][reg];
                e = fmaxf(e, 0.f);
                s = fmaf(vv[nt], e, s);
            }
            // reduce over the 16 lanes of this quad (the h direction)
#pragma unroll
            for (int off = 1; off < 16; off <<= 1) s += __shfl_xor(s, off, 16);
            if (r == 0) part[w][mt * 16 + quad * 4 + reg] = s;
        }
    }
    __syncthreads();
    if (tid < 64) {
        float sc = part[0][tid] + part[1][tid] + part[2][tid] + part[3][tid];
        scores[b * T_SZ + t0 + tid] = sc;
    }
}

// Kernel 3: softmax over t (4096) per batch row
__global__ __launch_bounds__(256) void softmax_kernel(
    const float* __restrict__ scores, float* __restrict__ out)
{
    const int b   = blockIdx.x;    // 32
    const int tid = threadIdx.x;   // 256, each handles 16 strided elements
    const float* s = scores + b * T_SZ;
    float*       o = out    + b * T_SZ;

    float loc[16];
    float m = -3.0e38f;
#pragma unroll
    for (int i = 0; i < 16; ++i) {
        loc[i] = s[tid + i * 256];
        m = fmaxf(m, loc[i]);
    }
    __shared__ float redm[4], reds[4];
#pragma unroll
    for (int off = 32; off > 0; off >>= 1) m = fmaxf(m, __shfl_xor(m, off, 64));
    if ((tid & 63) == 0) redm[tid >> 6] = m;
    __syncthreads();
    m = fmaxf(fmaxf(redm[0], redm[1]), fmaxf(redm[2], redm[3]));

    float sum = 0.f;
#pragma unroll
    for (int i = 0; i < 16; ++i) {
        loc[i] = __expf(loc[i] - m);
        sum += loc[i];
    }
#pragma unroll
    for (int off = 32; off > 0; off >>= 1) sum += __shfl_xor(sum, off, 64);
    if ((tid & 63) == 0) reds[tid >> 6] = sum;
    __syncthreads();
    sum = reds[0] + reds[1] + reds[2] + reds[3];
    const float inv = 1.0f / sum;
#pragma unroll
    for (int i = 0; i < 16; ++i) o[tid + i * 256] = loc[i] * inv;
}

extern "C" void kernel_launch(void* const* d_in, const int* in_sizes, int n_in,
                              void* d_out, int out_size, void* d_ws, size_t ws_size,
                              hipStream_t stream) {
    const float* hidden = (const float*)d_in[0];   // [B,H]
    const float* enc    = (const float*)d_in[1];   // [T,B,H]
    const float* attn_w = (const float*)d_in[2];   // [H,2H]
    const float* attn_b = (const float*)d_in[3];   // [H]
    const float* v      = (const float*)d_in[4];   // [H]
    float* out = (float*)d_out;                    // [B,1,T] = [B,T]

    float* hp     = (float*)d_ws;                  // [B,H]  (32 KiB)
    float* scores = hp + B_SZ * H_SZ;              // [B,T]  (512 KiB)

    hipLaunchKernelGGL(hproj_kernel, dim3(B_SZ), dim3(H_SZ), 0, stream,
                       hidden, attn_w, attn_b, hp);
    hipLaunchKernelGGL(attn_main, dim3(B_SZ * (T_SZ / 64)), dim3(256), 0, stream,
                       enc, attn_w, hp, v, scores);
    hipLaunchKernelGGL(softmax_kernel, dim3(B_SZ), dim3(256), 0, stream,
                       scores, out);
}

// Round 2
// 228.772 us; speedup vs baseline: 1.3625x; 1.3625x over previous
//
#include <hip/hip_runtime.h>
#include <hip/hip_bf16.h>

// Problem constants
#define B_SZ 32
#define T_SZ 4096
#define H_SZ 256
#define BH   (B_SZ * H_SZ)      // 8192 floats: stride between consecutive t in enc[T,B,H]
#define LDS_ROW 264             // 256 + 8 bf16 pad (row stride 132 dwords -> near-uniform banks)

typedef __attribute__((ext_vector_type(8))) short bf16x8;
typedef __attribute__((ext_vector_type(4))) float f32x4;

// fp32 -> bf16 bits, round-to-nearest-even (inputs are finite normals)
static __device__ __forceinline__ short f2bf(float x) {
    unsigned u = __float_as_uint(x);
    u += 0x7fffu + ((u >> 16) & 1u);
    return (short)(u >> 16);
}

static __device__ __forceinline__ bf16x8 cvt8(f32x4 a, f32x4 b) {
    bf16x8 r;
    r[0] = f2bf(a[0]); r[1] = f2bf(a[1]); r[2] = f2bf(a[2]); r[3] = f2bf(a[3]);
    r[4] = f2bf(b[0]); r[5] = f2bf(b[1]); r[6] = f2bf(b[2]); r[7] = f2bf(b[3]);
    return r;
}

// Prep kernel: one block per h (256 blocks, 256 threads).
//  (a) wbf[h][k] = bf16(We[h][k])  (We = attn_w[:, 256:512], k-contiguous)
//  (b) hp[b][h]  = hidden[b,:] . Wh[h,:] + attn_b[h]   for all 32 b
__global__ __launch_bounds__(256) void prep_kernel(
    const float* __restrict__ hidden, const float* __restrict__ attn_w,
    const float* __restrict__ attn_b, float* __restrict__ hp,
    short* __restrict__ wbf)
{
    const int h   = blockIdx.x;
    const int tid = threadIdx.x;
    __shared__ float wsh[H_SZ];

    // coalesced: whole wave reads contiguous attn_w row h
    wsh[tid] = attn_w[(size_t)h * 512 + tid];                       // Wh[h][tid]
    wbf[(size_t)h * H_SZ + tid] = f2bf(attn_w[(size_t)h * 512 + 256 + tid]); // We row -> bf16
    __syncthreads();

    const int b  = tid >> 3;        // 0..31
    const int kg = tid & 7;         // 0..7, 32 k each
    const float* hrow = hidden + b * H_SZ + kg * 32;
    const float* wrow = wsh + kg * 32;
    float s = 0.f;
#pragma unroll
    for (int j = 0; j < 32; j += 4) {
        f32x4 hv = *(const f32x4*)(hrow + j);
        s = fmaf(hv[0], wrow[j + 0], s);
        s = fmaf(hv[1], wrow[j + 1], s);
        s = fmaf(hv[2], wrow[j + 2], s);
        s = fmaf(hv[3], wrow[j + 3], s);
    }
#pragma unroll
    for (int off = 1; off < 8; off <<= 1) s += __shfl_xor(s, off, 8);
    if (kg == 0) hp[b * H_SZ + h] = s + attn_b[h];
}

// Main kernel: block = (b, 64-t tile). 256 threads = 4 waves.
// Stage enc tile 64t x 256k as bf16 in LDS (coalesced fp32 reads, convert once),
// then each wave does a 64t x 64h MFMA tile with B-fragments from the bf16
// weight buffer (L2-resident), prefetched one k-chunk ahead.
__global__ __launch_bounds__(256, 4) void attn_main(
    const float* __restrict__ enc,    // [T,B,H]
    const short* __restrict__ wbf,    // [H][256] bf16 We
    const float* __restrict__ hp,     // [B,H]
    const float* __restrict__ v,      // [H]
    float* __restrict__ scores)       // [B,T]
{
    __shared__ __align__(16) short As[64 * LDS_ROW];   // ~33 KB
    __shared__ float part[4][64];

    const int blk = blockIdx.x;
    const int b   = blk >> 6;
    const int t0  = (blk & 63) << 6;
    const int tid = threadIdx.x;
    const int w    = tid >> 6;
    const int lane = tid & 63;
    const int r    = lane & 15;
    const int quad = lane >> 4;
    const int hbase = w * 64;

    // ---- Stage A tile: 64 rows x 1 KB, fully coalesced, 16 loads in flight ----
    const float* encB = enc + b * H_SZ;
    f32x4 ld[16];
#pragma unroll
    for (int i = 0; i < 8; ++i) {
        const int idx = i * 256 + tid;
        const int row = idx >> 5, k8 = idx & 31;
        const float* p = encB + (size_t)(t0 + row) * BH + k8 * 8;
        ld[2 * i]     = *(const f32x4*)p;
        ld[2 * i + 1] = *(const f32x4*)(p + 4);
    }

    // Prefetch B fragments for kc=0 (overlaps the staging drain)
    bf16x8 bf_cur[4];
    {
        const int k = quad * 8;
#pragma unroll
        for (int nt = 0; nt < 4; ++nt)
            bf_cur[nt] = *(const bf16x8*)(wbf + (size_t)(hbase + nt * 16 + r) * H_SZ + k);
    }

#pragma unroll
    for (int i = 0; i < 8; ++i) {
        const int idx = i * 256 + tid;
        const int row = idx >> 5, k8 = idx & 31;
        *(bf16x8*)(&As[row * LDS_ROW + k8 * 8]) = cvt8(ld[2 * i], ld[2 * i + 1]);
    }
    __syncthreads();

    // ---- MFMA main loop over K=256 in chunks of 32 ----
    f32x4 acc[4][4];
#pragma unroll
    for (int mt = 0; mt < 4; ++mt)
#pragma unroll
        for (int nt = 0; nt < 4; ++nt)
            acc[mt][nt] = (f32x4){0.f, 0.f, 0.f, 0.f};

#pragma unroll 1
    for (int kc = 0; kc < 8; ++kc) {
        const int k = kc * 32 + quad * 8;
        bf16x8 afrag[4];
#pragma unroll
        for (int mt = 0; mt < 4; ++mt)
            afrag[mt] = *(const bf16x8*)(&As[(mt * 16 + r) * LDS_ROW + k]);

        bf16x8 bf_nxt[4];
        if (kc < 7) {
            const int kn = (kc + 1) * 32 + quad * 8;
#pragma unroll
            for (int nt = 0; nt < 4; ++nt)
                bf_nxt[nt] = *(const bf16x8*)(wbf + (size_t)(hbase + nt * 16 + r) * H_SZ + kn);
        }

#pragma unroll
        for (int mt = 0; mt < 4; ++mt)
#pragma unroll
            for (int nt = 0; nt < 4; ++nt)
                acc[mt][nt] = __builtin_amdgcn_mfma_f32_16x16x32_bf16(
                    afrag[mt], bf_cur[nt], acc[mt][nt], 0, 0, 0);

#pragma unroll
        for (int nt = 0; nt < 4; ++nt) bf_cur[nt] = bf_nxt[nt];
    }

    // ---- Epilogue: relu(hp + eproj) dot v, reduce over h ----
    float hpv[4], vv[4];
#pragma unroll
    for (int nt = 0; nt < 4; ++nt) {
        const int h = hbase + nt * 16 + r;        // C/D col = lane&15
        hpv[nt] = hp[b * H_SZ + h];
        vv[nt]  = v[h];
    }

#pragma unroll
    for (int mt = 0; mt < 4; ++mt) {
#pragma unroll
        for (int reg = 0; reg < 4; ++reg) {       // C/D row = quad*4 + reg
            float s = 0.f;
#pragma unroll
            for (int nt = 0; nt < 4; ++nt) {
                float e = hpv[nt] + acc[mt][nt][reg];
                e = fmaxf(e, 0.f);
                s = fmaf(vv[nt], e, s);
            }
#pragma unroll
            for (int off = 1; off < 16; off <<= 1) s += __shfl_xor(s, off, 16);
            if (r == 0) part[w][mt * 16 + quad * 4 + reg] = s;
        }
    }
    __syncthreads();
    if (tid < 64) {
        float sc = part[0][tid] + part[1][tid] + part[2][tid] + part[3][tid];
        scores[b * T_SZ + t0 + tid] = sc;
    }
}

// Softmax over t (4096) per batch row
__global__ __launch_bounds__(256) void softmax_kernel(
    const float* __restrict__ scores, float* __restrict__ out)
{
    const int b   = blockIdx.x;
    const int tid = threadIdx.x;
    const float* s = scores + b * T_SZ;
    float*       o = out    + b * T_SZ;

    float loc[16];
    float m = -3.0e38f;
#pragma unroll
    for (int i = 0; i < 16; ++i) {
        loc[i] = s[tid + i * 256];
        m = fmaxf(m, loc[i]);
    }
    __shared__ float redm[4], reds[4];
#pragma unroll
    for (int off = 32; off > 0; off >>= 1) m = fmaxf(m, __shfl_xor(m, off, 64));
    if ((tid & 63) == 0) redm[tid >> 6] = m;
    __syncthreads();
    m = fmaxf(fmaxf(redm[0], redm[1]), fmaxf(redm[2], redm[3]));

    float sum = 0.f;
#pragma unroll
    for (int i = 0; i < 16; ++i) {
        loc[i] = __expf(loc[i] - m);
        sum += loc[i];
    }
#pragma unroll
    for (int off = 32; off > 0; off >>= 1) sum += __shfl_xor(sum, off, 64);
    if ((tid & 63) == 0) reds[tid >> 6] = sum;
    __syncthreads();
    sum = reds[0] + reds[1] + reds[2] + reds[3];
    const float inv = 1.0f / sum;
#pragma unroll
    for (int i = 0; i < 16; ++i) o[tid + i * 256] = loc[i] * inv;
}

extern "C" void kernel_launch(void* const* d_in, const int* in_sizes, int n_in,
                              void* d_out, int out_size, void* d_ws, size_t ws_size,
                              hipStream_t stream) {
    const float* hidden = (const float*)d_in[0];   // [B,H]
    const float* enc    = (const float*)d_in[1];   // [T,B,H]
    const float* attn_w = (const float*)d_in[2];   // [H,2H]
    const float* attn_b = (const float*)d_in[3];   // [H]
    const float* v      = (const float*)d_in[4];   // [H]
    float* out = (float*)d_out;                    // [B,1,T] = [B,T]

    float* hp     = (float*)d_ws;                  // [B,H]   32 KB
    float* scores = hp + B_SZ * H_SZ;              // [B,T]   512 KB
    short* wbf    = (short*)(scores + B_SZ * T_SZ);// [H][256] bf16, 128 KB

    hipLaunchKernelGGL(prep_kernel, dim3(H_SZ), dim3(256), 0, stream,
                       hidden, attn_w, attn_b, hp, wbf);
    hipLaunchKernelGGL(attn_main, dim3(B_SZ * (T_SZ / 64)), dim3(256), 0, stream,
                       enc, wbf, hp, v, scores);
    hipLaunchKernelGGL(softmax_kernel, dim3(B_SZ), dim3(256), 0, stream,
                       scores, out);
}

// Round 3
// 225.356 us; speedup vs baseline: 1.3831x; 1.0152x over previous
//
#include <hip/hip_runtime.h>
#include <hip/hip_bf16.h>

// Problem constants
#define B_SZ 32
#define T_SZ 4096
#define H_SZ 256
#define BH   8192        // floats between consecutive t in enc[T,B,H]
#define SROW 72          // shorts per LDS row: 64 k + 8 pad (36 dwords -> conflict-min)

typedef __attribute__((ext_vector_type(8))) short bf16x8;
typedef __attribute__((ext_vector_type(4))) float f32x4;

// fp32 -> bf16 bits, round-to-nearest-even
static __device__ __forceinline__ short f2bf(float x) {
    unsigned u = __float_as_uint(x);
    u += 0x7fffu + ((u >> 16) & 1u);
    return (short)(u >> 16);
}

static __device__ __forceinline__ bf16x8 cvt8(f32x4 a, f32x4 b) {
    bf16x8 r;
    r[0] = f2bf(a[0]); r[1] = f2bf(a[1]); r[2] = f2bf(a[2]); r[3] = f2bf(a[3]);
    r[4] = f2bf(b[0]); r[5] = f2bf(b[1]); r[6] = f2bf(b[2]); r[7] = f2bf(b[3]);
    return r;
}

// Prep: (a) wbf[h][k] = bf16(We[h][k]); (b) hp[b][h] = hidden[b,:].Wh[h,:] + attn_b[h]
__global__ __launch_bounds__(256) void prep_kernel(
    const float* __restrict__ hidden, const float* __restrict__ attn_w,
    const float* __restrict__ attn_b, float* __restrict__ hp,
    short* __restrict__ wbf)
{
    const int h   = blockIdx.x;
    const int tid = threadIdx.x;
    __shared__ float wsh[H_SZ];

    wsh[tid] = attn_w[(size_t)h * 512 + tid];                                // Wh row
    wbf[(size_t)h * H_SZ + tid] = f2bf(attn_w[(size_t)h * 512 + 256 + tid]); // We row -> bf16
    __syncthreads();

    const int b  = tid >> 3;
    const int kg = tid & 7;
    const float* hrow = hidden + b * H_SZ + kg * 32;
    const float* wrow = wsh + kg * 32;
    float s = 0.f;
#pragma unroll
    for (int j = 0; j < 32; j += 4) {
        f32x4 hv = *(const f32x4*)(hrow + j);
        s = fmaf(hv[0], wrow[j + 0], s);
        s = fmaf(hv[1], wrow[j + 1], s);
        s = fmaf(hv[2], wrow[j + 2], s);
        s = fmaf(hv[3], wrow[j + 3], s);
    }
#pragma unroll
    for (int off = 1; off < 8; off <<= 1) s += __shfl_xor(s, off, 8);
    if (kg == 0) hp[b * H_SZ + h] = s + attn_b[h];
}

// Main: block = (b, 64-t tile), 4 waves. K pipelined in 4 chunks of 64,
// double-buffered bf16 LDS; staging loads for chunk k+1 in flight during
// compute of chunk k. Wave w owns h-slice [64w, 64w+64).
__global__ __launch_bounds__(256, 3) void attn_main(
    const float* __restrict__ enc,    // [T,B,H]
    const short* __restrict__ wbf,    // [H][256] bf16
    const float* __restrict__ hp,     // [B,H]
    const float* __restrict__ v,      // [H]
    float* __restrict__ scores)       // [B,T]
{
    __shared__ __align__(16) short As[2][64 * SROW];  // 2 x 9216 B
    __shared__ float part[4][64];

    const int blk  = blockIdx.x;
    const int b    = blk >> 6;
    const int t0   = (blk & 63) << 6;
    const int tid  = threadIdx.x;
    const int w    = tid >> 6;
    const int lane = tid & 63;
    const int r    = lane & 15;
    const int quad = lane >> 4;
    const int hbase = w * 64;

    // staging map: thread -> (row = tid>>2, 16-float quarter q = tid&3)
    const int srow = tid >> 2, sq = tid & 3;
    const float* sp = enc + (size_t)b * H_SZ + (size_t)(t0 + srow) * BH + sq * 16;
    short* sd0 = &As[0][0] + srow * SROW + sq * 16;
    short* sd1 = &As[1][0] + srow * SROW + sq * 16;

    // per-wave weight fragment pointers (k-contiguous rows of wbf)
    const short* wp0 = wbf + (size_t)(hbase + 0 * 16 + r) * H_SZ + quad * 8;
    const short* wp1 = wbf + (size_t)(hbase + 1 * 16 + r) * H_SZ + quad * 8;
    const short* wp2 = wbf + (size_t)(hbase + 2 * 16 + r) * H_SZ + quad * 8;
    const short* wp3 = wbf + (size_t)(hbase + 3 * 16 + r) * H_SZ + quad * 8;

    f32x4 acc[4][4];
#pragma unroll
    for (int mt = 0; mt < 4; ++mt)
#pragma unroll
        for (int nt = 0; nt < 4; ++nt)
            acc[mt][nt] = (f32x4){0.f, 0.f, 0.f, 0.f};

    // ---- Prologue: B fragments for chunk 0 (both ksteps), then stage chunk 0 ----
    bf16x8 bc[2][4];
#pragma unroll
    for (int s = 0; s < 2; ++s) {
        bc[s][0] = *(const bf16x8*)(wp0 + s * 32);
        bc[s][1] = *(const bf16x8*)(wp1 + s * 32);
        bc[s][2] = *(const bf16x8*)(wp2 + s * 32);
        bc[s][3] = *(const bf16x8*)(wp3 + s * 32);
    }
    {
        f32x4 st[4];
#pragma unroll
        for (int j = 0; j < 4; ++j) st[j] = *(const f32x4*)(sp + 4 * j);
        ((bf16x8*)sd0)[0] = cvt8(st[0], st[1]);
        ((bf16x8*)sd0)[1] = cvt8(st[2], st[3]);
    }
    __syncthreads();

    // ---- Pipelined main loop: 4 chunks of 64 k ----
#pragma unroll
    for (int kc = 0; kc < 4; ++kc) {
        // 1) issue staging loads for chunk kc+1 (in flight during compute)
        f32x4 stn[4];
        if (kc < 3) {
#pragma unroll
            for (int j = 0; j < 4; ++j)
                stn[j] = *(const f32x4*)(sp + (kc + 1) * 64 + 4 * j);
        }

        // 2) compute 2 ksteps of this chunk from LDS
        const short* abase = &As[kc & 1][0] + quad * 8;
#pragma unroll
        for (int s = 0; s < 2; ++s) {
            bf16x8 af[4];
#pragma unroll
            for (int mt = 0; mt < 4; ++mt)
                af[mt] = *(const bf16x8*)(abase + (mt * 16 + r) * SROW + s * 32);
#pragma unroll
            for (int mt = 0; mt < 4; ++mt)
#pragma unroll
                for (int nt = 0; nt < 4; ++nt)
                    acc[mt][nt] = __builtin_amdgcn_mfma_f32_16x16x32_bf16(
                        af[mt], bc[s][nt], acc[mt][nt], 0, 0, 0);
        }

        // 3) issue B fragments for chunk kc+1 (consumed after the barrier;
        //    barrier drain covers their latency)
        if (kc < 3) {
            const int ko = (kc + 1) * 64;
#pragma unroll
            for (int s = 0; s < 2; ++s) {
                bc[s][0] = *(const bf16x8*)(wp0 + ko + s * 32);
                bc[s][1] = *(const bf16x8*)(wp1 + ko + s * 32);
                bc[s][2] = *(const bf16x8*)(wp2 + ko + s * 32);
                bc[s][3] = *(const bf16x8*)(wp3 + ko + s * 32);
            }
            // 4) convert + store staged chunk, flip buffer
            short* d = ((kc + 1) & 1) ? sd1 : sd0;
            ((bf16x8*)d)[0] = cvt8(stn[0], stn[1]);
            ((bf16x8*)d)[1] = cvt8(stn[2], stn[3]);
            __syncthreads();
        }
    }

    // ---- Epilogue: relu(hp + eproj) dot v, reduce over h ----
    float hpv[4], vv[4];
#pragma unroll
    for (int nt = 0; nt < 4; ++nt) {
        const int h = hbase + nt * 16 + r;        // C/D col = lane&15
        hpv[nt] = hp[b * H_SZ + h];
        vv[nt]  = v[h];
    }

#pragma unroll
    for (int mt = 0; mt < 4; ++mt) {
#pragma unroll
        for (int reg = 0; reg < 4; ++reg) {       // C/D row = quad*4 + reg
            float s = 0.f;
#pragma unroll
            for (int nt = 0; nt < 4; ++nt) {
                float e = hpv[nt] + acc[mt][nt][reg];
                e = fmaxf(e, 0.f);
                s = fmaf(vv[nt], e, s);
            }
#pragma unroll
            for (int off = 1; off < 16; off <<= 1) s += __shfl_xor(s, off, 16);
            if (r == 0) part[w][mt * 16 + quad * 4 + reg] = s;
        }
    }
    __syncthreads();
    if (tid < 64) {
        float sc = part[0][tid] + part[1][tid] + part[2][tid] + part[3][tid];
        scores[b * T_SZ + t0 + tid] = sc;
    }
}

// Softmax over t (4096) per batch row; 1024 threads for latency hiding
__global__ __launch_bounds__(1024) void softmax_kernel(
    const float* __restrict__ scores, float* __restrict__ out)
{
    const int b   = blockIdx.x;
    const int tid = threadIdx.x;
    const float* s = scores + b * T_SZ;
    float*       o = out    + b * T_SZ;

    float loc[4];
    float m = -3.0e38f;
#pragma unroll
    for (int i = 0; i < 4; ++i) {
        loc[i] = s[tid + i * 1024];
        m = fmaxf(m, loc[i]);
    }
    __shared__ float redm[16], reds[16];
#pragma unroll
    for (int off = 32; off > 0; off >>= 1) m = fmaxf(m, __shfl_xor(m, off, 64));
    if ((tid & 63) == 0) redm[tid >> 6] = m;
    __syncthreads();
#pragma unroll
    for (int i = 0; i < 16; ++i) m = fmaxf(m, redm[i]);

    float sum = 0.f;
#pragma unroll
    for (int i = 0; i < 4; ++i) {
        loc[i] = __expf(loc[i] - m);
        sum += loc[i];
    }
#pragma unroll
    for (int off = 32; off > 0; off >>= 1) sum += __shfl_xor(sum, off, 64);
    if ((tid & 63) == 0) reds[tid >> 6] = sum;
    __syncthreads();
    sum = 0.f;
#pragma unroll
    for (int i = 0; i < 16; ++i) sum += reds[i];
    const float inv = 1.0f / sum;
#pragma unroll
    for (int i = 0; i < 4; ++i) o[tid + i * 1024] = loc[i] * inv;
}

extern "C" void kernel_launch(void* const* d_in, const int* in_sizes, int n_in,
                              void* d_out, int out_size, void* d_ws, size_t ws_size,
                              hipStream_t stream) {
    const float* hidden = (const float*)d_in[0];   // [B,H]
    const float* enc    = (const float*)d_in[1];   // [T,B,H]
    const float* attn_w = (const float*)d_in[2];   // [H,2H]
    const float* attn_b = (const float*)d_in[3];   // [H]
    const float* v      = (const float*)d_in[4];   // [H]
    float* out = (float*)d_out;                    // [B,1,T]

    float* hp     = (float*)d_ws;                  // [B,H]   32 KB
    float* scores = hp + B_SZ * H_SZ;              // [B,T]   512 KB
    short* wbf    = (short*)(scores + B_SZ * T_SZ);// [H][256] bf16, 128 KB

    hipLaunchKernelGGL(prep_kernel, dim3(H_SZ), dim3(256), 0, stream,
                       hidden, attn_w, attn_b, hp, wbf);
    hipLaunchKernelGGL(attn_main, dim3(B_SZ * (T_SZ / 64)), dim3(256), 0, stream,
                       enc, wbf, hp, v, scores);
    hipLaunchKernelGGL(softmax_kernel, dim3(B_SZ), dim3(1024), 0, stream,
                       scores, out);
}